// Round 17
// baseline (171.815 us; speedup 1.0000x reference)
//
#include <hip/hip_runtime.h>

typedef unsigned int uint;
typedef unsigned short ushort;
using short8 = __attribute__((ext_vector_type(8))) short;   // 8 bf16 (4 VGPRs)
using f32x4  = __attribute__((ext_vector_type(4))) float;

#define NHALF 2048
#define DIM   1024
#define MROWS 4096
#define KMED  8388607u
#define NTRI  528            // 32*33/2 lower-triangle 128x128 blocks

// workspace layout (bytes)
#define L2_OFF   0ull                          // 64 MB f32 (lower 128-blocks valid only)
#define GHA_OFF  67108864ull                   // 64 KB: 16384-bin hist of bits 29:16 (+low-count word at [16384])
#define SEL_OFF  (GHA_OFF + 65600ull)          // 64 B: selF[2]=itb
#define ACC_OFF  (SEL_OFF + 64ull)             // 16 B: double accumulator
#define CNT_OFF  (ACC_OFF + 16ull)             // 32 B: counters (gemm, loss)
#define ZERO_WORDS 16428                       // (65600+64+16+32)/4 from GHA_OFF

#define AGLOAD(p) __hip_atomic_load((p), __ATOMIC_RELAXED, __HIP_MEMORY_SCOPE_AGENT)

__device__ __forceinline__ ushort f2bf(float x) {
    uint u = __float_as_uint(x);
    u += 0x7FFFu + ((u >> 16) & 1u);           // RNE
    return (ushort)(u >> 16);
}

// ---------------------------------------------------------------- dispatch 1: fused convert + MFMA GEMM + hist + median tail
// reg-stage: f32 global -> regs -> bf16 cvt (+ exact sq accumulation) -> LDS
#define STAGE_STEP(nb, kk0) do {                                                           \
    float4 a0 = *(const float4*)(pA + (size_t)r0 * DIM + (kk0) + c4);                      \
    float4 a1 = *(const float4*)(pA + (size_t)(r0 + 64) * DIM + (kk0) + c4);               \
    float4 bb0 = *(const float4*)(pB + (size_t)r0 * DIM + (kk0) + c4);                     \
    float4 bb1 = *(const float4*)(pB + (size_t)(r0 + 64) * DIM + (kk0) + c4);              \
    sA0 += a0.x*a0.x + a0.y*a0.y + a0.z*a0.z + a0.w*a0.w;                                  \
    sA1 += a1.x*a1.x + a1.y*a1.y + a1.z*a1.z + a1.w*a1.w;                                  \
    sB0 += bb0.x*bb0.x + bb0.y*bb0.y + bb0.z*bb0.z + bb0.w*bb0.w;                          \
    sB1 += bb1.x*bb1.x + bb1.y*bb1.y + bb1.z*bb1.z + bb1.w*bb1.w;                          \
    ushort4 ua0; ua0.x = f2bf(a0.x); ua0.y = f2bf(a0.y); ua0.z = f2bf(a0.z); ua0.w = f2bf(a0.w); \
    ushort4 ua1; ua1.x = f2bf(a1.x); ua1.y = f2bf(a1.y); ua1.z = f2bf(a1.z); ua1.w = f2bf(a1.w); \
    ushort4 ub0; ub0.x = f2bf(bb0.x); ub0.y = f2bf(bb0.y); ub0.z = f2bf(bb0.z); ub0.w = f2bf(bb0.w); \
    ushort4 ub1; ub1.x = f2bf(bb1.x); ub1.y = f2bf(bb1.y); ub1.z = f2bf(bb1.z); ub1.w = f2bf(bb1.w); \
    *(ushort4*)(&lds[nb][0][r0][c4])      = ua0;                                           \
    *(ushort4*)(&lds[nb][0][r0 + 64][c4]) = ua1;                                           \
    *(ushort4*)(&lds[nb][1][r0][c4])      = ub0;                                           \
    *(ushort4*)(&lds[nb][1][r0 + 64][c4]) = ub1;                                           \
} while (0)

__global__ __launch_bounds__(512, 4) void gemm_kernel(const float* __restrict__ src,
                                                      const float* __restrict__ tgt,
                                                      char* __restrict__ wsb,
                                                      float* __restrict__ out) {
    float* L2   = (float*)(wsb + L2_OFF);
    uint*  gha  = (uint*)(wsb + GHA_OFF);
    float* selF = (float*)(wsb + SEL_OFF);
    uint*  cnt  = (uint*)(wsb + CNT_OFF);

    // union: bf16 staging [2buf][2arr][128][32] (32 KB) / 16384-bin u16-packed hist (32 KB)
    __shared__ __align__(16) uint shmem[8192];
    __shared__ float sqA[128], sqB[128];
    __shared__ uint lowcnt;
    ushort (*lds)[2][128][32] = (ushort (*)[2][128][32])shmem;

    int t = threadIdx.x;
    int bid = (int)blockIdx.x;

    // zero global scratch (all 528 blocks co-resident at t~0: 33KB LDS -> 4 blocks/CU
    // capacity 1024; flushes happen only after the ~40us K-loop)
    {
        int g = bid * 512 + t;
        if (g < ZERO_WORDS)
            __hip_atomic_store(&gha[g], 0u, __ATOMIC_RELAXED, __HIP_MEMORY_SCOPE_AGENT);
    }
    if (t < 128) { sqA[t] = 0.0f; sqB[t] = 0.0f; }
    if (t == 0) lowcnt = 0;

    // XCD swizzle (528 = 8*66, bijective) then triangular decode
    int b = bid;
    b = (b & 7) * 66 + (b >> 3);
    int bi = (int)((sqrtf(8.0f * (float)b + 1.0f) - 1.0f) * 0.5f);
    while ((bi + 1) * (bi + 2) / 2 <= b) ++bi;
    while (bi * (bi + 1) / 2 > b) --bi;
    int bj = b - bi * (bi + 1) / 2;          // bj <= bi

    int lane = t & 63, wid = t >> 6;         // 8 waves
    int wm = wid >> 2, wn = wid & 3;         // 2x4 wave grid: 64 rows x 32 cols per wave
    int rowbase = bi * 128, colbase = bj * 128;

    const float* pA = (rowbase < NHALF) ? src + (size_t)rowbase * DIM
                                        : tgt + (size_t)(rowbase - NHALF) * DIM;
    const float* pB = (colbase < NHALF) ? src + (size_t)colbase * DIM
                                        : tgt + (size_t)(colbase - NHALF) * DIM;

    f32x4 acc[4][2] = {};
    int fr = lane & 15, fk = (lane >> 4) * 8;
    int r0 = t >> 3;                 // 0..63 (staging row)
    int c4 = (t & 7) * 4;            // staging col within 32-chunk
    float sA0 = 0.0f, sA1 = 0.0f, sB0 = 0.0f, sB1 = 0.0f;

    STAGE_STEP(0, 0);                // prologue: k-step 0 into buffer 0
    __syncthreads();

    int cur = 0;
    for (int kt = 0; kt < 32; ++kt) {
        if (kt < 31) {                        // stage k-step kt+1 into the other buffer
            int nb = cur ^ 1;
            STAGE_STEP(nb, (kt + 1) * 32);
        }
        short8 fa[4], fb[2];
#pragma unroll
        for (int m = 0; m < 4; ++m)
            fa[m] = *reinterpret_cast<const short8*>(&lds[cur][0][wm * 64 + m * 16 + fr][fk]);
#pragma unroll
        for (int n = 0; n < 2; ++n)
            fb[n] = *reinterpret_cast<const short8*>(&lds[cur][1][wn * 32 + n * 16 + fr][fk]);
#pragma unroll
        for (int m = 0; m < 4; ++m)
#pragma unroll
            for (int n = 0; n < 2; ++n)
                acc[m][n] = __builtin_amdgcn_mfma_f32_16x16x32_bf16(fa[m], fb[n], acc[m][n], 0, 0, 0);
        __syncthreads();                      // writes of kt+1 visible; readers of cur done
        cur ^= 1;
    }

    // block-local exact sq reduce (8 partial lanes per row)
    atomicAdd(&sqA[r0],      sA0);
    atomicAdd(&sqA[r0 + 64], sA1);
    atomicAdd(&sqB[r0],      sB0);
    atomicAdd(&sqB[r0 + 64], sB1);
    __syncthreads();

    // ---- epilogue: L2 store + fused hist.  bit30=1 (>=2.0): bin = bits[29:16] in LDS;
    //      bit30=0 (rare): block-local counter -> one global atomic.
    uint* h = shmem;                          // 8192 packed words = 32 KB
    for (int i = t; i < 8192; i += 512) h[i] = 0;
    __syncthreads();

    uint w = (bi == bj) ? 1u : 2u;
    int fq = lane >> 4;
#pragma unroll
    for (int m = 0; m < 4; ++m) {
#pragma unroll
        for (int n = 0; n < 2; ++n) {
            int gj = colbase + wn * 32 + n * 16 + fr;
            float sqj = sqB[wn * 32 + n * 16 + fr];
#pragma unroll
            for (int r = 0; r < 4; ++r) {
                int gi = rowbase + wm * 64 + m * 16 + fq * 4 + r;
                float sqi = sqA[wm * 64 + m * 16 + fq * 4 + r];
                float v = fmaxf(sqi + sqj - 2.0f * acc[m][n][r], 0.0f);
                L2[(size_t)gi * MROWS + gj] = v;
                uint bits = __float_as_uint(v);
                if (bits & 0x40000000u) {
                    uint k14 = (bits >> 16) & 0x3FFFu;
                    atomicAdd(&h[k14 >> 1], (k14 & 1) ? (w << 16) : w);
                } else {
                    atomicAdd(&lowcnt, w);
                }
            }
        }
    }
    __syncthreads();
    for (int i = t; i < 8192; i += 512) {      // flush nonzero bins to global
        uint wd = h[i];
        if (wd) {
            uint lo = wd & 0xFFFFu, hi2 = wd >> 16;
            if (lo)  atomicAdd(&gha[2 * i],     lo);
            if (hi2) atomicAdd(&gha[2 * i + 1], hi2);
        }
    }
    if (t == 0 && lowcnt) atomicAdd(&gha[16384], lowcnt);

    // ---- last-block tail: median select -> bandwidth + itb (threadFenceReduction pattern)
    __syncthreads();
    if (t == 0) {
        __threadfence();
        h[0] = (atomicAdd(&cnt[0], 1u) == gridDim.x - 1) ? 1u : 0u;
    }
    __syncthreads();
    bool last = h[0] != 0;
    __syncthreads();
    if (last) {
        uint* part = h + 16;       // 512
        uint* loc  = h + 544;      // 2
        uint* lin  = h + 560;      // 32
        uint s = 0;
        for (int i = 0; i < 32; ++i) s += AGLOAD(&gha[t * 32 + i]);   // 512 thr x 32 bins
        part[t] = s;
        __syncthreads();
        if (t == 0) {
            uint k = KMED - AGLOAD(&gha[16384]);   // below-2.0 values rank below everything
            uint cum = 0; int seg = 0;
            for (; seg < 512; ++seg) { uint c = part[seg]; if (cum + c > k) break; cum += c; }
            loc[0] = (uint)seg; loc[1] = k - cum;
        }
        __syncthreads();
        int seg = (int)loc[0];
        if (t < 32) lin[t] = AGLOAD(&gha[seg * 32 + t]);
        __syncthreads();
        if (t == 0) {
            uint k = loc[1], cum = 0; int bb = 0;
            for (; bb < 32; ++bb) { uint c = lin[bb]; if (cum + c > k) break; cum += c; }
            // median resolved to bits >= 16; bin midpoint (err <= 8 abs @ ~2048)
            uint mbits = 0x40000000u | ((uint)(seg * 32 + bb) << 16) | 0x8000u;
            float median = __uint_as_float(mbits);
            float logn = logf(2048.0f + 1e-8f);
            float bw = sqrtf(0.5f * median / logn);
            out[1] = bw;                               // bandwidth
            selF[2] = logn / median;                   // 1/(2 bw^2)
        }
    }
}

// ---------------------------------------------------------------- dispatch 2: loss reduce + last-block finalize
__global__ __launch_bounds__(256) void loss_kernel(char* __restrict__ wsb,
                                                   float* __restrict__ out) {
    const float* L2   = (const float*)(wsb + L2_OFF);
    const float* selF = (const float*)(wsb + SEL_OFF);
    double* accd = (double*)(wsb + ACC_OFF);
    uint*   cnt  = (uint*)(wsb + CNT_OFF);
    __shared__ float fred[4];
    __shared__ uint flag;
    float itb = selF[2];                       // 1/(2 bw^2)
    int t = threadIdx.x;
    float local = 0.0f;
    for (int rr = blockIdx.x; rr < NHALF; rr += gridDim.x) {
#pragma unroll
        for (int half = 0; half < 2; ++half) {
            int row = half ? (MROWS - 1 - rr) : rr;   // paired rows: constant work/block
            int nc = ((row >> 7) + 1) << 7;
            int diaglo = (row >> 7) << 7;
            bool rlow = row < NHALF;
            const float4* rp = reinterpret_cast<const float4*>(L2 + (size_t)row * MROWS);
            for (int q = t; q < (nc >> 2); q += 256) {
                float4 v = rp[q];
                int j0 = q << 2;
                float w = (j0 >= diaglo) ? 1.0f : 2.0f;
                float sgn = ((j0 < NHALF) == rlow) ? w : -w;   // NHALF is 128-block aligned
                float s = __expf(-v.x * itb) + __expf(-v.y * itb) +
                          __expf(-v.z * itb) + __expf(-v.w * itb);
                local += sgn * s;
            }
        }
    }
    for (int o = 32; o; o >>= 1) local += __shfl_down(local, o);
    if ((t & 63) == 0) fred[t >> 6] = local;
    __syncthreads();
    if (t == 0) {
        atomicAdd(accd, (double)(fred[0] + fred[1] + fred[2] + fred[3]));
        __threadfence();
        flag = (atomicAdd(&cnt[1], 1u) == gridDim.x - 1) ? 1u : 0u;
    }
    __syncthreads();
    if (flag && t == 0) {
        double a = __hip_atomic_load(accd, __ATOMIC_RELAXED, __HIP_MEMORY_SCOPE_AGENT);
        out[0] = (float)(a / 4194304.0);       // mean over N*N, N=2048
    }
}

// ---------------------------------------------------------------- launch (2 dispatches)
extern "C" void kernel_launch(void* const* d_in, const int* in_sizes, int n_in,
                              void* d_out, int out_size, void* d_ws, size_t ws_size,
                              hipStream_t stream) {
    const float* src = (const float*)d_in[0];
    const float* tgt = (const float*)d_in[1];
    float* out = (float*)d_out;
    char* ws = (char*)d_ws;

    gemm_kernel<<<NTRI, 512, 0, stream>>>(src, tgt, ws, out);
    loss_kernel<<<2048, 256, 0, stream>>>(ws, out);
}